// Round 11
// baseline (1188.810 us; speedup 1.0000x reference)
//
#include <hip/hip_runtime.h>

#define D_IN   1024
#define D_SAE  16384
#define KTOP   32
#define NROWS  8192
#define KSPLIT 3072   // A: [lo*2048 | hi | hi],  B: [hi | lo*2048 | hi]
#define LOSCALE 2048.0f
#define INV_LOSCALE 4.8828125e-4f   // 2^-11, exact
#define CAND_CAP 512
#define NCHUNK 256                   // 64-elem chunks per row

typedef _Float16 f16x8 __attribute__((ext_vector_type(8)));
typedef float    f32x4 __attribute__((ext_vector_type(4)));

__device__ __forceinline__ unsigned int f2su(float f) {
    unsigned int b = __float_as_uint(f);
    return (b & 0x80000000u) ? ~b : (b | 0x80000000u);
}
__device__ __forceinline__ float su2f(unsigned int su) {
    unsigned int fb = (su & 0x80000000u) ? (su & 0x7fffffffu) : ~su;
    return __uint_as_float(fb);
}
__device__ __forceinline__ unsigned short f2bf(float f) {   // RN bf16
    unsigned int u = __float_as_uint(f);
    return (unsigned short)((u + 0x7fffu + ((u >> 16) & 1u)) >> 16);
}

// ---------------------------------------------------------------------------
// Fused split kernel: fp32 -> (hi, lo*2048) fp16 for both x and W_enc.
// ---------------------------------------------------------------------------
__global__ __launch_bounds__(256) void split_xw(
    const float* __restrict__ x, const float* __restrict__ b_pre,
    const float* __restrict__ W_enc,
    _Float16* __restrict__ A2, _Float16* __restrict__ B2)
{
    const int b   = blockIdx.x;
    const int tid = threadIdx.x;
    const int k   = tid * 4;
    if (b < NROWS) {
        float4 v  = *(const float4*)(x + (size_t)b * D_IN + k);
        float4 bp = *(const float4*)(b_pre + k);
        v.x -= bp.x; v.y -= bp.y; v.z -= bp.z; v.w -= bp.w;
        _Float16 h[4], l[4];
        h[0] = (_Float16)v.x; l[0] = (_Float16)((v.x - (float)h[0]) * LOSCALE);
        h[1] = (_Float16)v.y; l[1] = (_Float16)((v.y - (float)h[1]) * LOSCALE);
        h[2] = (_Float16)v.z; l[2] = (_Float16)((v.z - (float)h[2]) * LOSCALE);
        h[3] = (_Float16)v.w; l[3] = (_Float16)((v.w - (float)h[3]) * LOSCALE);
        _Float16* row = A2 + (size_t)b * KSPLIT;
        *(ulong1*)(row + k)        = *(ulong1*)l;
        *(ulong1*)(row + 1024 + k) = *(ulong1*)h;
        *(ulong1*)(row + 2048 + k) = *(ulong1*)h;
    } else {
        const int s = b - NROWS;
        float4 v = *(const float4*)(W_enc + (size_t)s * D_IN + k);
        _Float16 h[4], l[4];
        h[0] = (_Float16)v.x; l[0] = (_Float16)((v.x - (float)h[0]) * LOSCALE);
        h[1] = (_Float16)v.y; l[1] = (_Float16)((v.y - (float)h[1]) * LOSCALE);
        h[2] = (_Float16)v.z; l[2] = (_Float16)((v.z - (float)h[2]) * LOSCALE);
        h[3] = (_Float16)v.w; l[3] = (_Float16)((v.w - (float)h[3]) * LOSCALE);
        _Float16* row = B2 + (size_t)s * KSPLIT;
        *(ulong1*)(row + k)        = *(ulong1*)h;
        *(ulong1*)(row + 1024 + k) = *(ulong1*)l;
        *(ulong1*)(row + 2048 + k) = *(ulong1*)h;
    }
}

// ---------------------------------------------------------------------------
// Kernel 1 (v4.1): 256x256 tile, BK=64, 8 waves, 4 phases/tile, T2 swizzle,
// quarter-granular staging with COUNTED vmcnt waits. Issues/phase = 3,3,1,1;
// waits: end-P0 vmcnt(3) WHEN PREFETCHING (vmcnt(0) on the final tile --
// R10's race: with no new issues, vmcnt(3) was a no-op and P1 read Aq1/Aq3
// still in flight), end-P3 vmcnt(2).
// Ledger: (a) buf c^1 writes begin after the barrier ending t-1 P3 (reads
// drained by lgkmcnt(0)); (b) end-P3 vmcnt(2) leaves only {Aq1,Aq3} ->
// B*,Aq0,Aq2 landed before t+1 P0 reads; (c) end-P0 wait leaves only the 3
// new issues -> Aq1,Aq3 landed before t+1 P1 (drain-all when none issued).
// Fused per-(row,chunk) max epilogue. K=3072, rescale at t=32.
// ---------------------------------------------------------------------------
__device__ __forceinline__ void gload_lds16(const void* g, void* lds) {
    __builtin_amdgcn_global_load_lds(
        (const __attribute__((address_space(1))) unsigned int*)g,
        (__attribute__((address_space(3))) unsigned int*)lds, 16, 0, 0);
}

// Stage one 64-row quarter of one matrix (1 gload_lds16 per thread).
// Source pre-swizzled by row&7 (16B granule); LDS dest linear.
__device__ __forceinline__ void stage_q(
    const _Float16* __restrict__ gbase, _Float16* lds,
    int q, int k0, int wid, int lane)
{
    const int srow = lane >> 3;                  // 0..7
    const int row  = q * 64 + wid * 8 + srow;
    const int col  = ((lane & 7) ^ srow) * 8;    // pre-swizzled k-offset
    gload_lds16(gbase + (size_t)row * KSPLIT + k0 + col,
                lds + (size_t)(q * 64 + wid * 8) * 64);
}

__global__ __launch_bounds__(512, 2) void encode_mfma256p(
    const _Float16* __restrict__ A2, const _Float16* __restrict__ B2,
    float* __restrict__ z_pre, unsigned int* __restrict__ cmax_g)
{
    __shared__ _Float16 Asl[2][256 * 64];   // 2 x 32 KB
    __shared__ _Float16 Bsl[2][256 * 64];   // 2 x 32 KB

    const int tid  = threadIdx.x;
    const int wid  = tid >> 6;          // 0..7
    const int lane = tid & 63;
    const int wr   = wid >> 2;          // 0..1  (M half: 128 rows)
    const int wc   = wid & 3;           // 0..3  (N quarter: 64 cols)
    const int brow = blockIdx.y * 256;
    const int bcol = blockIdx.x * 256;

    const int fr = lane & 15;
    const int fq = lane >> 4;
    const int slot0 = ((0 + fq) ^ (fr & 7)) * 8;   // kk=0 swizzled k-slot
    const int slot1 = ((4 + fq) ^ (fr & 7)) * 8;   // kk=1 swizzled k-slot
    const int arow  = wr * 128 + fr;
    const int brw   = wc * 64 + fr;

    f32x4 acc[8][4] = {};
    f16x8 b[4];

    const _Float16* Ab = A2 + (size_t)brow * KSPLIT;
    const _Float16* Bb = B2 + (size_t)bcol * KSPLIT;

    // prologue: tile 0 fully staged
#pragma unroll
    for (int q = 0; q < 4; ++q) {
        stage_q(Ab, Asl[0], q, 0, wid, lane);
        stage_q(Bb, Bsl[0], q, 0, wid, lane);
    }
    asm volatile("s_waitcnt vmcnt(0)" ::: "memory");
    __builtin_amdgcn_s_barrier();

    for (int t = 0; t < 48; ++t) {
        const int cur = t & 1;
        const bool pre = (t < 47);
        const int k1 = (t + 1) * 64;
        const _Float16* Ac = Asl[cur];
        const _Float16* Bc = Bsl[cur];
        _Float16* An = Asl[cur ^ 1];
        _Float16* Bn = Bsl[cur ^ 1];

        if (t == 32) {   // K=2048 boundary: undo 2^11 lo-scale on cross terms
#pragma unroll
            for (int m = 0; m < 8; ++m)
#pragma unroll
                for (int n = 0; n < 4; ++n) {
                    acc[m][n][0] *= INV_LOSCALE; acc[m][n][1] *= INV_LOSCALE;
                    acc[m][n][2] *= INV_LOSCALE; acc[m][n][3] *= INV_LOSCALE;
                }
        }

#pragma unroll
        for (int ph = 0; ph < 4; ++ph) {
            const int kk = ph >> 1;                 // 0,0,1,1
            const int mh = ph & 1;                  // 0,1,0,1
            const int slot = kk ? slot1 : slot0;

            if (mh == 0) {                          // new kk: reload B frags
#pragma unroll
                for (int n = 0; n < 4; ++n)
                    b[n] = *(const f16x8*)&Bc[(brw + n * 16) * 64 + slot];
            }
            f16x8 a[4];
#pragma unroll
            for (int m = 0; m < 4; ++m)
                a[m] = *(const f16x8*)&Ac[(arow + mh * 64 + m * 16) * 64 + slot];

            if (pre) {                              // quarter-stage schedule
                if (ph == 0) {
                    stage_q(Bb, Bn, 0, k1, wid, lane);
                    stage_q(Bb, Bn, 1, k1, wid, lane);
                    stage_q(Ab, An, 0, k1, wid, lane);
                } else if (ph == 1) {
                    stage_q(Bb, Bn, 2, k1, wid, lane);
                    stage_q(Bb, Bn, 3, k1, wid, lane);
                    stage_q(Ab, An, 2, k1, wid, lane);
                } else if (ph == 2) {
                    stage_q(Ab, An, 1, k1, wid, lane);
                } else {
                    stage_q(Ab, An, 3, k1, wid, lane);
                }
            }

            __builtin_amdgcn_s_barrier();
            asm volatile("s_waitcnt lgkmcnt(0)" ::: "memory");
            __builtin_amdgcn_sched_barrier(0);
            __builtin_amdgcn_s_setprio(1);
#pragma unroll
            for (int m = 0; m < 4; ++m)
#pragma unroll
                for (int n = 0; n < 4; ++n)
                    acc[mh * 4 + m][n] = __builtin_amdgcn_mfma_f32_16x16x32_f16(
                        a[m], b[n], acc[mh * 4 + m][n], 0, 0, 0);
            __builtin_amdgcn_s_setprio(0);

            if (ph == 0) {
                // Aq1,Aq3 of PREV prefetch must land before P1 reads them.
                // With no new issues (final tile), vmcnt(3) would be a no-op
                // over the 2 stragglers -> must drain fully (R10 race fix).
                if (pre) {
                    asm volatile("s_waitcnt vmcnt(3)" ::: "memory");
                } else {
                    asm volatile("s_waitcnt vmcnt(0)" ::: "memory");
                }
                __builtin_amdgcn_sched_barrier(0);
            } else if (ph == 3) {   // B*,Aq0,Aq2 of THIS prefetch landed
                asm volatile("s_waitcnt vmcnt(2)" ::: "memory");
                __builtin_amdgcn_sched_barrier(0);
            }
            __builtin_amdgcn_s_barrier();
        }
    }

    // C write. C/D layout: col = lane&15, row = (lane>>4)*4 + j  [verified]
#pragma unroll
    for (int m = 0; m < 8; ++m) {
        const int r0 = brow + wr * 128 + m * 16 + fq * 4;
#pragma unroll
        for (int n = 0; n < 4; ++n) {
            float* dst = z_pre + (size_t)r0 * D_SAE + bcol + wc * 64 + n * 16 + fr;
#pragma unroll
            for (int j = 0; j < 4; ++j)
                dst[(size_t)j * D_SAE] = acc[m][n][j];
        }
    }

    // fused chunk-max: wave's 64-col chunk = [bcol + wc*64, +64)
    const int chunk = (bcol >> 6) + wc;
#pragma unroll
    for (int m = 0; m < 8; ++m) {
        float v[4];
#pragma unroll
        for (int j = 0; j < 4; ++j)
            v[j] = fmaxf(fmaxf(acc[m][0][j], acc[m][1][j]),
                         fmaxf(acc[m][2][j], acc[m][3][j]));
#pragma unroll
        for (int mask = 1; mask < 16; mask <<= 1) {
#pragma unroll
            for (int j = 0; j < 4; ++j)
                v[j] = fmaxf(v[j], __shfl_xor(v[j], mask));
        }
        if (fr == 0) {
#pragma unroll
            for (int j = 0; j < 4; ++j) {
                const int row = brow + wr * 128 + m * 16 + fq * 4 + j;
                cmax_g[(size_t)row * NCHUNK + chunk] = f2su(v[j]);
            }
        }
    }
}

// ---------------------------------------------------------------------------
// Kernel 1 (fallback): fp32 vector GEMM (unchanged)
// ---------------------------------------------------------------------------
__global__ __launch_bounds__(256, 2) void encode_gemm(
    const float* __restrict__ x, const float* __restrict__ b_pre,
    const float* __restrict__ W_enc, float* __restrict__ z_pre)
{
    __shared__ float As[16][132];
    __shared__ float Bs[16][132];
    const int tid = threadIdx.x;
    const int n0  = blockIdx.y * 128;
    const int s0  = blockIdx.x * 128;
    const int ty  = tid >> 4;
    const int tx  = tid & 15;
    const int r0  = tid >> 2;
    const int r1  = r0 + 64;
    const int kq  = (tid & 3) * 4;
    float acc[8][8];
#pragma unroll
    for (int i = 0; i < 8; ++i)
#pragma unroll
        for (int j = 0; j < 8; ++j) acc[i][j] = 0.0f;
    const float* xA = x     + (size_t)n0 * D_IN;
    const float* wB = W_enc + (size_t)s0 * D_IN;
    for (int k0 = 0; k0 < D_IN; k0 += 16) {
        float4 a0 = *(const float4*)(xA + (size_t)r0 * D_IN + k0 + kq);
        float4 a1 = *(const float4*)(xA + (size_t)r1 * D_IN + k0 + kq);
        float4 b0 = *(const float4*)(wB + (size_t)r0 * D_IN + k0 + kq);
        float4 b1 = *(const float4*)(wB + (size_t)r1 * D_IN + k0 + kq);
        float4 bp = *(const float4*)(b_pre + k0 + kq);
        a0.x -= bp.x; a0.y -= bp.y; a0.z -= bp.z; a0.w -= bp.w;
        a1.x -= bp.x; a1.y -= bp.y; a1.z -= bp.z; a1.w -= bp.w;
        __syncthreads();
        As[kq + 0][r0] = a0.x; As[kq + 1][r0] = a0.y; As[kq + 2][r0] = a0.z; As[kq + 3][r0] = a0.w;
        As[kq + 0][r1] = a1.x; As[kq + 1][r1] = a1.y; As[kq + 2][r1] = a1.z; As[kq + 3][r1] = a1.w;
        Bs[kq + 0][r0] = b0.x; Bs[kq + 1][r0] = b0.y; Bs[kq + 2][r0] = b0.z; Bs[kq + 3][r0] = b0.w;
        Bs[kq + 0][r1] = b1.x; Bs[kq + 1][r1] = b1.y; Bs[kq + 2][r1] = b1.z; Bs[kq + 3][r1] = b1.w;
        __syncthreads();
#pragma unroll
        for (int kk = 0; kk < 16; ++kk) {
            float4 av0 = *(const float4*)&As[kk][ty * 8];
            float4 av1 = *(const float4*)&As[kk][ty * 8 + 4];
            float4 bv0 = *(const float4*)&Bs[kk][tx * 8];
            float4 bv1 = *(const float4*)&Bs[kk][tx * 8 + 4];
            float a[8] = {av0.x, av0.y, av0.z, av0.w, av1.x, av1.y, av1.z, av1.w};
            float b[8] = {bv0.x, bv0.y, bv0.z, bv0.w, bv1.x, bv1.y, bv1.z, bv1.w};
#pragma unroll
            for (int i = 0; i < 8; ++i)
#pragma unroll
                for (int j = 0; j < 8; ++j)
                    acc[i][j] = fmaf(a[i], b[j], acc[i][j]);
        }
    }
#pragma unroll
    for (int i = 0; i < 8; ++i) {
        float* dst = z_pre + (size_t)(n0 + ty * 8 + i) * D_SAE + s0 + tx * 8;
        *(float4*)(dst)     = make_float4(acc[i][0], acc[i][1], acc[i][2], acc[i][3]);
        *(float4*)(dst + 4) = make_float4(acc[i][4], acc[i][5], acc[i][6], acc[i][7]);
    }
}

// fallback helper: build cmax from z_pre (only used with encode_gemm path)
__global__ __launch_bounds__(256) void cmax_from_zpre(
    const float* __restrict__ z_pre, unsigned int* __restrict__ cmax_g)
{
    const int row = blockIdx.x;
    const int c   = threadIdx.x;
    const float* src = z_pre + (size_t)row * D_SAE + c * 64;
    unsigned int mx = 0u;
    for (int e = 0; e < 64; ++e) mx = max(mx, f2su(src[e]));
    cmax_g[(size_t)row * NCHUNK + c] = mx;
}

// ---------------------------------------------------------------------------
// Kernel 2 (v5): top-K via chunk-max prefilter (R9-proven, unchanged).
// ---------------------------------------------------------------------------
__global__ __launch_bounds__(256) void topk_select5(
    const float* __restrict__ z_pre, const unsigned int* __restrict__ cmax_g,
    float* __restrict__ z, int* __restrict__ out_idx, float* __restrict__ out_val)
{
    __shared__ unsigned int cm[NCHUNK];
    __shared__ unsigned int s_sm32;
    __shared__ int          hot[NCHUNK];
    __shared__ unsigned int nhot;
    __shared__ unsigned int cand_su[CAND_CAP];
    __shared__ int          cand_idx[CAND_CAP];
    __shared__ unsigned int cand_cnt;
    __shared__ int   sidx[KTOP];
    __shared__ float sval[KTOP];
    __shared__ unsigned int bsu[256];
    __shared__ int          bidx[256];

    const int row  = blockIdx.x;
    const int tid  = threadIdx.x;
    const int wid  = tid >> 6;
    const int lane = tid & 63;
    const float* src = z_pre + (size_t)row * D_SAE;

    if (tid == 0) { nhot = 0u; cand_cnt = 0u; }
    cm[tid] = cmax_g[(size_t)row * NCHUNK + tid];
    __syncthreads();

    {
        const unsigned int v = cm[tid];
        int r = 0;
        for (int j = 0; j < NCHUNK; ++j)
            r += (cm[j] > v) || (cm[j] == v && j < tid);
        if (r == KTOP - 1) s_sm32 = v;
    }
    __syncthreads();
    const unsigned int sm32 = s_sm32;

    if (cm[tid] >= sm32) { unsigned int p = atomicAdd(&nhot, 1u); hot[p] = tid; }
    __syncthreads();

    const int nh = (int)nhot;
    for (int h = wid; h < nh; h += 4) {
        const int i = hot[h] * 64 + lane;
        const unsigned int su = f2su(src[i]);
        if (su >= sm32) {
            unsigned int p = atomicAdd(&cand_cnt, 1u);
            if (p < (unsigned)CAND_CAP) { cand_su[p] = su; cand_idx[p] = i; }
        }
    }
    __syncthreads();

    if (cand_cnt <= (unsigned)CAND_CAP) {
        const int cnt = (int)cand_cnt;
        for (int c = tid; c < cnt; c += 256) {
            const unsigned int s = cand_su[c];
            const int id = cand_idx[c];
            int r = 0;
            for (int j = 0; j < cnt; ++j) {
                const unsigned int sj = cand_su[j];
                r += (sj > s) || (sj == s && cand_idx[j] < id);
            }
            if (r < KTOP) { sidx[r] = id; sval[r] = su2f(s); }
        }
        __syncthreads();
    } else {
        unsigned int last_su = 0xFFFFFFFFu; int last_idx = -1;
        for (int r = 0; r < KTOP; ++r) {
            unsigned int mysu = 0u; int myidx = 0x7FFFFFFF;
            for (int i = tid; i < D_SAE; i += 256) {
                const unsigned int su = f2su(src[i]);
                const bool after = (su < last_su) || (su == last_su && i > last_idx);
                if (after && (su > mysu || (su == mysu && i < myidx))) {
                    mysu = su; myidx = i;
                }
            }
            bsu[tid] = mysu; bidx[tid] = myidx;
            __syncthreads();
            if (tid == 0) {
                unsigned int bs = 0u; int bi = 0x7FFFFFFF;
                for (int j = 0; j < 256; ++j) {
                    if (bsu[j] > bs || (bsu[j] == bs && bidx[j] < bi)) {
                        bs = bsu[j]; bi = bidx[j];
                    }
                }
                sidx[r] = bi; sval[r] = su2f(bs);
                bsu[0] = bs; bidx[0] = bi;
            }
            __syncthreads();
            last_su = bsu[0]; last_idx = bidx[0];
            __syncthreads();
        }
    }

    if (tid < KTOP) {
        const int id = sidx[tid];
        const float fv = sval[tid];
        z[(size_t)row * D_SAE + id] = fv;
        if (out_idx != nullptr) {
            int r = 0;
            for (int j = 0; j < KTOP; ++j) r += (sidx[j] < id);
            out_idx[row * KTOP + r] = id;
            out_val[row * KTOP + r] = fv;
        }
    }
}

// ---------------------------------------------------------------------------
// Kernel 2 (v4, no-workspace fallback path): full radix (unchanged).
// ---------------------------------------------------------------------------
__global__ __launch_bounds__(256) void topk_select4(
    const float* __restrict__ z_pre, float* __restrict__ z)
{
    __shared__ unsigned int hist[4096];
    __shared__ unsigned int cmax[256];
    __shared__ unsigned int sb[256];
    __shared__ unsigned int cand_su[CAND_CAP];
    __shared__ int          cand_idx[CAND_CAP];
    __shared__ unsigned int cand_cnt;
    __shared__ int          hot[256];
    __shared__ unsigned int nhot;
    __shared__ int   sel_list[KTOP];
    __shared__ float sel_val[KTOP];
    __shared__ int s_bin, s_gt;
    __shared__ unsigned int wcw[4];

    const int row  = blockIdx.x;
    const int tid  = threadIdx.x;
    const int wid  = tid >> 6;
    const int lane = tid & 63;
    const float* src = z_pre + (size_t)row * D_SAE;

    const int shifts[3] = {20, 8, 0};
    const int nbits_[3] = {12, 12, 8};

    cmax[tid] = 0u;
    if (tid == 0) { cand_cnt = 0u; nhot = 0u; }

    unsigned int prefix = 0u, pmask = 0u;
    int need = KTOP;
    int shiftF = 0;

    for (int level = 0; level < 3; ++level) {
        const int shift = shifts[level];
        const unsigned int nb = 1u << nbits_[level];
        for (int i = tid; i < (int)nb; i += 256) hist[i] = 0u;
        __syncthreads();
        for (int it = 0; it < 16; ++it) {
            const int i4 = (it * 256 + tid) * 4;
            float4 v = *(const float4*)(src + i4);
            unsigned int mx = 0u;
#pragma unroll
            for (int e = 0; e < 4; ++e) {
                unsigned int su = f2su((&v.x)[e]);
                if ((su & pmask) == prefix)
                    atomicAdd(&hist[(su >> shift) & (nb - 1u)], 1u);
                mx = su > mx ? su : mx;
            }
            if (level == 0) atomicMax(&cmax[i4 >> 6], mx);
        }
        __syncthreads();
        const int bpt = (int)(nb >> 8);
        unsigned int lsum = 0u;
        for (int j = 0; j < bpt; ++j) lsum += hist[tid * bpt + j];
        sb[tid] = lsum;
        __syncthreads();
        for (int off = 1; off < 256; off <<= 1) {
            unsigned int v = (tid + off < 256) ? sb[tid + off] : 0u;
            __syncthreads();
            sb[tid] += v;
            __syncthreads();
        }
        {
            unsigned int ge = sb[tid];
            unsigned int gt = (tid < 255) ? sb[tid + 1] : 0u;
            if ((int)ge >= need && (int)gt < need) {
                unsigned int run = gt;
                for (int j = bpt - 1; j >= 0; --j) {
                    unsigned int c = hist[tid * bpt + j];
                    if ((int)(run + c) >= need) { s_bin = tid * bpt + j; s_gt = (int)run; break; }
                    run += c;
                }
            }
        }
        __syncthreads();
        const int b = s_bin; const int gt = s_gt; const int cntb = (int)hist[b];
        __syncthreads();
        need -= gt;
        prefix |= ((unsigned int)b) << shift;
        pmask  |= (nb - 1u) << shift;
        if (cntb <= CAND_CAP) { shiftF = shift; break; }
        if (level == 2)       { shiftF = 0;     break; }
    }
    const unsigned int hb = prefix >> shiftF;

    if (cmax[tid] >= prefix) { unsigned int p = atomicAdd(&nhot, 1u); hot[p] = tid; }
    __syncthreads();

    __shared__ unsigned int outcnt;
    if (tid == 0) outcnt = 0u;
    __syncthreads();
    const int nh = (int)nhot;
    for (int h = wid; h < nh; h += 4) {
        const int i = hot[h] * 64 + lane;
        const float f = src[i];
        const unsigned int su = f2su(f);
        const unsigned int cls = su >> shiftF;
        if (cls > hb) {
            z[(size_t)row * D_SAE + i] = f;
        } else if (cls == hb) {
            unsigned int p = atomicAdd(&cand_cnt, 1u);
            if (p < (unsigned)CAND_CAP) { cand_su[p] = su; cand_idx[p] = i; }
        }
    }
    __syncthreads();

    if (cand_cnt <= (unsigned)CAND_CAP) {
        const int cnt = (int)cand_cnt;
        for (int c = tid; c < cnt; c += 256) {
            const unsigned int s = cand_su[c];
            const int id = cand_idx[c];
            int r = 0;
            for (int j = 0; j < cnt; ++j) {
                const unsigned int sj = cand_su[j];
                r += (sj > s) || (sj == s && cand_idx[j] < id);
            }
            if (r < need) { sel_list[r] = id; sel_val[r] = su2f(s); }
        }
        __syncthreads();
    } else {
        int cum = 0;
        for (int seg = 0; seg < 64; ++seg) {
            const int i = seg * 256 + tid;
            const bool m = (f2su(src[i]) == prefix);
            const unsigned long long bm = __ballot(m);
            if (lane == 0) wcw[wid] = (unsigned int)__popcll(bm);
            __syncthreads();
            int base = cum;
            for (int w = 0; w < wid; ++w) base += (int)wcw[w];
            const int r = base + (int)__popcll(bm & ((1ull << lane) - 1ull));
            if (m && r < need) { sel_list[r] = i; sel_val[r] = su2f(prefix); }
            cum += (int)(wcw[0] + wcw[1] + wcw[2] + wcw[3]);
            __syncthreads();
            if (cum >= need) break;
        }
        __syncthreads();
    }
    if (tid < need) z[(size_t)row * D_SAE + sel_list[tid]] = sel_val[tid];
}

// ---------------------------------------------------------------------------
// Kernel 3: W_dec transpose -> bf16 WdT (unchanged)
// ---------------------------------------------------------------------------
__global__ __launch_bounds__(256) void transpose_wdec_bf16(
    const float* __restrict__ in, unsigned short* __restrict__ out)
{
    __shared__ float tile[32][33];
    const int tid = threadIdx.x;
    const int lx = tid & 31, ly = tid >> 5;
    const int j0 = blockIdx.x * 32;
    const int d0 = blockIdx.y * 32;
#pragma unroll
    for (int r = 0; r < 4; ++r) {
        int d = d0 + ly + r * 8;
        tile[ly + r * 8][lx] = in[(size_t)d * D_SAE + j0 + lx];
    }
    __syncthreads();
#pragma unroll
    for (int r = 0; r < 4; ++r) {
        int j = j0 + ly + r * 8;
        out[(size_t)j * D_IN + d0 + lx] = f2bf(tile[lx][ly + r * 8]);
    }
}

// ---------------------------------------------------------------------------
// Kernel 4a: sparse decode from (idx,val) lists, bf16 WdT (unchanged)
// ---------------------------------------------------------------------------
__global__ __launch_bounds__(256) void decode_fast_bf16(
    const unsigned short* __restrict__ WdT, const int* __restrict__ idx,
    const float* __restrict__ val, const float* __restrict__ b_pre,
    const float* __restrict__ b_dec, float* __restrict__ x_hat)
{
    __shared__ int   sj[KTOP];
    __shared__ float sv[KTOP];
    const int row = blockIdx.x, tid = threadIdx.x;
    if (tid < KTOP) { sj[tid] = idx[row * KTOP + tid]; sv[tid] = val[row * KTOP + tid]; }
    __syncthreads();
    const int d = tid * 4;
    float4 bd = *(const float4*)(b_dec + d);
    float4 bp = *(const float4*)(b_pre + d);
    float4 acc = make_float4(bd.x + bp.x, bd.y + bp.y, bd.z + bp.z, bd.w + bp.w);
#pragma unroll
    for (int j = 0; j < KTOP; ++j) {
        const float v = sv[j];
        const ushort4 w = *(const ushort4*)(WdT + (size_t)sj[j] * D_IN + d);
        acc.x = fmaf(v, __uint_as_float((unsigned int)w.x << 16), acc.x);
        acc.y = fmaf(v, __uint_as_float((unsigned int)w.y << 16), acc.y);
        acc.z = fmaf(v, __uint_as_float((unsigned int)w.z << 16), acc.z);
        acc.w = fmaf(v, __uint_as_float((unsigned int)w.w << 16), acc.w);
    }
    *(float4*)(x_hat + (size_t)row * D_IN + d) = acc;
}

// ---------------------------------------------------------------------------
// Kernel 4b: fallback decode (unchanged)
// ---------------------------------------------------------------------------
__global__ __launch_bounds__(256) void decode_slow(
    const float* __restrict__ W_dec, const float* __restrict__ z,
    const float* __restrict__ b_pre, const float* __restrict__ b_dec,
    float* __restrict__ x_hat)
{
    __shared__ int   sj[64];
    __shared__ float sv[64];
    __shared__ unsigned int cnt;
    __shared__ int s_m;
    const int row = blockIdx.x, tid = threadIdx.x;
    if (tid == 0) cnt = 0u;
    __syncthreads();
    const float* zr = z + (size_t)row * D_SAE;
    for (int i = tid; i < D_SAE; i += 256) {
        float v = zr[i];
        if (v != 0.0f) { unsigned p = atomicAdd(&cnt, 1u); if (p < 64u) { sj[p] = i; sv[p] = v; } }
    }
    __syncthreads();
    if (tid == 0) {
        int m = (int)(cnt < 64u ? cnt : 64u);
        for (int a = 1; a < m; ++a) {
            int vi = sj[a]; float vv = sv[a]; int b = a - 1;
            while (b >= 0 && sj[b] > vi) { sj[b + 1] = sj[b]; sv[b + 1] = sv[b]; --b; }
            sj[b + 1] = vi; sv[b + 1] = vv;
        }
        s_m = m;
    }
    __syncthreads();
    const int m = s_m;
    const int d = tid * 4;
    float4 bd = *(const float4*)(b_dec + d);
    float4 bp = *(const float4*)(b_pre + d);
    float4 acc = make_float4(bd.x + bp.x, bd.y + bp.y, bd.z + bp.z, bd.w + bp.w);
    for (int j = 0; j < m; ++j) {
        float v = sv[j];
        size_t c = (size_t)sj[j];
        acc.x = fmaf(v, W_dec[(size_t)(d + 0) * D_SAE + c], acc.x);
        acc.y = fmaf(v, W_dec[(size_t)(d + 1) * D_SAE + c], acc.y);
        acc.z = fmaf(v, W_dec[(size_t)(d + 2) * D_SAE + c], acc.z);
        acc.w = fmaf(v, W_dec[(size_t)(d + 3) * D_SAE + c], acc.w);
    }
    *(float4*)(x_hat + (size_t)row * D_IN + d) = acc;
}

// ---------------------------------------------------------------------------
extern "C" void kernel_launch(void* const* d_in, const int* in_sizes, int n_in,
                              void* d_out, int out_size, void* d_ws, size_t ws_size,
                              hipStream_t stream)
{
    const float* x     = (const float*)d_in[0];
    const float* b_pre = (const float*)d_in[1];
    const float* W_enc = (const float*)d_in[2];
    const float* W_dec = (const float*)d_in[3];
    const float* b_dec = (const float*)d_in[4];

    float* x_hat = (float*)d_out;
    float* z     = x_hat + (size_t)NROWS * D_IN;
    float* z_pre = z + (size_t)NROWS * D_SAE;

    const size_t wdt_bytes  = (size_t)D_SAE * D_IN * sizeof(unsigned short); // bf16
    const size_t list_bytes = (size_t)NROWS * KTOP * (sizeof(int) + sizeof(float));
    const size_t cmax_bytes = (size_t)NROWS * NCHUNK * sizeof(unsigned int);
    const size_t a2_bytes   = (size_t)NROWS * KSPLIT * sizeof(_Float16);
    const size_t b2_bytes   = (size_t)D_SAE * KSPLIT * sizeof(_Float16);

    char* p = (char*)d_ws;
    unsigned short* WdT  = (unsigned short*)p;  p += wdt_bytes;
    int*            idxl = (int*)p;             p += (size_t)NROWS * KTOP * sizeof(int);
    float*          vall = (float*)p;           p += (size_t)NROWS * KTOP * sizeof(float);
    unsigned int*   cmax = (unsigned int*)p;    p += cmax_bytes;
    _Float16*       A2   = (_Float16*)p;        p += a2_bytes;
    _Float16*       B2   = (_Float16*)p;

    const bool fast = (ws_size >= wdt_bytes + list_bytes + cmax_bytes);
    const bool mfma = (ws_size >= wdt_bytes + list_bytes + cmax_bytes + a2_bytes + b2_bytes);

    // z written sparsely by top-k -- zero it up front (stream-ordered)
    hipMemsetAsync(z, 0, (size_t)NROWS * D_SAE * sizeof(float), stream);

    if (mfma) {
        split_xw<<<NROWS + D_SAE, 256, 0, stream>>>(x, b_pre, W_enc, A2, B2);
        encode_mfma256p<<<dim3(D_SAE / 256, NROWS / 256), 512, 0, stream>>>(A2, B2, z_pre, cmax);
    } else {
        encode_gemm<<<dim3(D_SAE / 128, NROWS / 128), 256, 0, stream>>>(x, b_pre, W_enc, z_pre);
        if (fast) cmax_from_zpre<<<NROWS, 256, 0, stream>>>(z_pre, cmax);
    }

    if (fast) {
        transpose_wdec_bf16<<<dim3(D_SAE / 32, D_IN / 32), 256, 0, stream>>>(W_dec, WdT);
        topk_select5<<<NROWS, 256, 0, stream>>>(z_pre, cmax, z, idxl, vall);
        decode_fast_bf16<<<NROWS, 256, 0, stream>>>(WdT, idxl, vall, b_pre, b_dec, x_hat);
    } else {
        topk_select4<<<NROWS, 256, 0, stream>>>(z_pre, z);
        decode_slow<<<NROWS, 256, 0, stream>>>(W_dec, z, b_pre, b_dec, x_hat);
    }
}

// Round 12
// 1143.849 us; speedup vs baseline: 1.0393x; 1.0393x over previous
//
#include <hip/hip_runtime.h>

#define D_IN   1024
#define D_SAE  16384
#define KTOP   32
#define NROWS  8192
#define KSPLIT 3072   // A: [lo*2048 | hi | hi],  B: [hi | lo*2048 | hi]
#define LOSCALE 2048.0f
#define INV_LOSCALE 4.8828125e-4f   // 2^-11, exact
#define CAND_CAP 512
#define NCHUNK 256                   // 64-elem chunks per row

typedef _Float16 f16x8 __attribute__((ext_vector_type(8)));
typedef float    f32x4 __attribute__((ext_vector_type(4)));

__device__ __forceinline__ unsigned int f2su(float f) {
    unsigned int b = __float_as_uint(f);
    return (b & 0x80000000u) ? ~b : (b | 0x80000000u);
}
__device__ __forceinline__ float su2f(unsigned int su) {
    unsigned int fb = (su & 0x80000000u) ? (su & 0x7fffffffu) : ~su;
    return __uint_as_float(fb);
}
__device__ __forceinline__ unsigned short f2bf(float f) {   // RN bf16
    unsigned int u = __float_as_uint(f);
    return (unsigned short)((u + 0x7fffu + ((u >> 16) & 1u)) >> 16);
}

// ---------------------------------------------------------------------------
// Fused split kernel: fp32 -> (hi, lo*2048) fp16 for both x and W_enc.
// ---------------------------------------------------------------------------
__global__ __launch_bounds__(256) void split_xw(
    const float* __restrict__ x, const float* __restrict__ b_pre,
    const float* __restrict__ W_enc,
    _Float16* __restrict__ A2, _Float16* __restrict__ B2)
{
    const int b   = blockIdx.x;
    const int tid = threadIdx.x;
    const int k   = tid * 4;
    if (b < NROWS) {
        float4 v  = *(const float4*)(x + (size_t)b * D_IN + k);
        float4 bp = *(const float4*)(b_pre + k);
        v.x -= bp.x; v.y -= bp.y; v.z -= bp.z; v.w -= bp.w;
        _Float16 h[4], l[4];
        h[0] = (_Float16)v.x; l[0] = (_Float16)((v.x - (float)h[0]) * LOSCALE);
        h[1] = (_Float16)v.y; l[1] = (_Float16)((v.y - (float)h[1]) * LOSCALE);
        h[2] = (_Float16)v.z; l[2] = (_Float16)((v.z - (float)h[2]) * LOSCALE);
        h[3] = (_Float16)v.w; l[3] = (_Float16)((v.w - (float)h[3]) * LOSCALE);
        _Float16* row = A2 + (size_t)b * KSPLIT;
        *(ulong1*)(row + k)        = *(ulong1*)l;
        *(ulong1*)(row + 1024 + k) = *(ulong1*)h;
        *(ulong1*)(row + 2048 + k) = *(ulong1*)h;
    } else {
        const int s = b - NROWS;
        float4 v = *(const float4*)(W_enc + (size_t)s * D_IN + k);
        _Float16 h[4], l[4];
        h[0] = (_Float16)v.x; l[0] = (_Float16)((v.x - (float)h[0]) * LOSCALE);
        h[1] = (_Float16)v.y; l[1] = (_Float16)((v.y - (float)h[1]) * LOSCALE);
        h[2] = (_Float16)v.z; l[2] = (_Float16)((v.z - (float)h[2]) * LOSCALE);
        h[3] = (_Float16)v.w; l[3] = (_Float16)((v.w - (float)h[3]) * LOSCALE);
        _Float16* row = B2 + (size_t)s * KSPLIT;
        *(ulong1*)(row + k)        = *(ulong1*)h;
        *(ulong1*)(row + 1024 + k) = *(ulong1*)l;
        *(ulong1*)(row + 2048 + k) = *(ulong1*)h;
    }
}

// ---------------------------------------------------------------------------
// Kernel 1: encode MFMA GEMM -- R9-proven 128x128 / 2-barrier / T2 swizzle
// structure (deep-pipeline variants tested R5/R6/R11: all slower; reverted).
// + fused per-(row,chunk) max epilogue + z-region zeroing (replaces memset).
// K=3072, acc rescale x2^-11 at k=2048.
// ---------------------------------------------------------------------------
__device__ __forceinline__ void gload_lds16(const void* g, void* lds) {
    __builtin_amdgcn_global_load_lds(
        (const __attribute__((address_space(1))) unsigned int*)g,
        (__attribute__((address_space(3))) unsigned int*)lds, 16, 0, 0);
}

__global__ __launch_bounds__(256, 2) void encode_mfma(
    const _Float16* __restrict__ A2, const _Float16* __restrict__ B2,
    float* __restrict__ z_pre, unsigned int* __restrict__ cmax_g,
    float* __restrict__ z)
{
    __shared__ _Float16 Asl[128 * 64];
    __shared__ _Float16 Bsl[128 * 64];

    const int tid  = threadIdx.x;
    const int wid  = tid >> 6;
    const int lane = tid & 63;
    const int wr   = wid >> 1;
    const int wc   = wid & 1;
    const int brow = blockIdx.y * 128;
    const int bcol = blockIdx.x * 128;

    const int srow = lane >> 3;
    const int scol = ((lane & 7) ^ srow) * 8;      // pre-swizzled global col

    const int fr = lane & 15;
    const int fq = lane >> 4;
    const int slot0 = ((0 + fq) ^ (fr & 7)) * 8;
    const int slot1 = ((4 + fq) ^ (fr & 7)) * 8;

    f32x4 acc[4][4] = {};

    for (int k0 = 0; k0 < KSPLIT; k0 += 64) {
        if (k0 == 2048) {
#pragma unroll
            for (int m = 0; m < 4; ++m)
#pragma unroll
                for (int n = 0; n < 4; ++n) {
                    acc[m][n][0] *= INV_LOSCALE;
                    acc[m][n][1] *= INV_LOSCALE;
                    acc[m][n][2] *= INV_LOSCALE;
                    acc[m][n][3] *= INV_LOSCALE;
                }
        }
#pragma unroll
        for (int t = 0; t < 4; ++t) {
            const int rg = (wid * 4 + t) * 8 + srow;
            const char* ldsA = (const char*)Asl + (wid * 4 + t) * 1024;
            const char* ldsB = (const char*)Bsl + (wid * 4 + t) * 1024;
            gload_lds16(A2 + (size_t)(brow + rg) * KSPLIT + k0 + scol, (void*)ldsA);
            gload_lds16(B2 + (size_t)(bcol + rg) * KSPLIT + k0 + scol, (void*)ldsB);
        }
        __syncthreads();

#pragma unroll
        for (int kk = 0; kk < 2; ++kk) {
            const int slot = kk ? slot1 : slot0;
            f16x8 a[4], b[4];
#pragma unroll
            for (int m = 0; m < 4; ++m)
                a[m] = *(const f16x8*)&Asl[(wr * 64 + m * 16 + fr) * 64 + slot];
#pragma unroll
            for (int n = 0; n < 4; ++n)
                b[n] = *(const f16x8*)&Bsl[(wc * 64 + n * 16 + fr) * 64 + slot];
#pragma unroll
            for (int m = 0; m < 4; ++m)
#pragma unroll
                for (int n = 0; n < 4; ++n)
                    acc[m][n] = __builtin_amdgcn_mfma_f32_16x16x32_f16(a[m], b[n], acc[m][n], 0, 0, 0);
        }
        __syncthreads();
    }

    // C write. C/D layout: col = lane&15, row = (lane>>4)*4 + j  [verified]
#pragma unroll
    for (int m = 0; m < 4; ++m) {
        const int r0 = brow + wr * 64 + m * 16 + fq * 4;
#pragma unroll
        for (int n = 0; n < 4; ++n) {
            float* dst = z_pre + (size_t)r0 * D_SAE + bcol + wc * 64 + n * 16 + fr;
#pragma unroll
            for (int j = 0; j < 4; ++j)
                dst[(size_t)j * D_SAE] = acc[m][n][j];
        }
    }

    // zero this block's 128x128 region of z (replaces global memset):
    // thread t zeroes 64 contiguous floats of row (t>>1), half (t&1).
    {
        const int zr = brow + (tid >> 1);
        float* zp = z + (size_t)zr * D_SAE + bcol + (tid & 1) * 64;
        const float4 z4 = make_float4(0.f, 0.f, 0.f, 0.f);
#pragma unroll
        for (int q = 0; q < 16; ++q) *(float4*)(zp + q * 4) = z4;
    }

    // fused chunk-max: wave's 64-col chunk = [bcol + wc*64, +64), rows 64.
    const int chunk = (bcol >> 6) + wc;
#pragma unroll
    for (int m = 0; m < 4; ++m) {
        float v[4];
#pragma unroll
        for (int j = 0; j < 4; ++j)
            v[j] = fmaxf(fmaxf(acc[m][0][j], acc[m][1][j]),
                         fmaxf(acc[m][2][j], acc[m][3][j]));
#pragma unroll
        for (int mask = 1; mask < 16; mask <<= 1) {
#pragma unroll
            for (int j = 0; j < 4; ++j)
                v[j] = fmaxf(v[j], __shfl_xor(v[j], mask));
        }
        if (fr == 0) {
#pragma unroll
            for (int j = 0; j < 4; ++j) {
                const int row = brow + wr * 64 + m * 16 + fq * 4 + j;
                cmax_g[(size_t)row * NCHUNK + chunk] = f2su(v[j]);
            }
        }
    }
}

// ---------------------------------------------------------------------------
// Kernel 1 (fallback): fp32 vector GEMM (unchanged)
// ---------------------------------------------------------------------------
__global__ __launch_bounds__(256, 2) void encode_gemm(
    const float* __restrict__ x, const float* __restrict__ b_pre,
    const float* __restrict__ W_enc, float* __restrict__ z_pre)
{
    __shared__ float As[16][132];
    __shared__ float Bs[16][132];
    const int tid = threadIdx.x;
    const int n0  = blockIdx.y * 128;
    const int s0  = blockIdx.x * 128;
    const int ty  = tid >> 4;
    const int tx  = tid & 15;
    const int r0  = tid >> 2;
    const int r1  = r0 + 64;
    const int kq  = (tid & 3) * 4;
    float acc[8][8];
#pragma unroll
    for (int i = 0; i < 8; ++i)
#pragma unroll
        for (int j = 0; j < 8; ++j) acc[i][j] = 0.0f;
    const float* xA = x     + (size_t)n0 * D_IN;
    const float* wB = W_enc + (size_t)s0 * D_IN;
    for (int k0 = 0; k0 < D_IN; k0 += 16) {
        float4 a0 = *(const float4*)(xA + (size_t)r0 * D_IN + k0 + kq);
        float4 a1 = *(const float4*)(xA + (size_t)r1 * D_IN + k0 + kq);
        float4 b0 = *(const float4*)(wB + (size_t)r0 * D_IN + k0 + kq);
        float4 b1 = *(const float4*)(wB + (size_t)r1 * D_IN + k0 + kq);
        float4 bp = *(const float4*)(b_pre + k0 + kq);
        a0.x -= bp.x; a0.y -= bp.y; a0.z -= bp.z; a0.w -= bp.w;
        a1.x -= bp.x; a1.y -= bp.y; a1.z -= bp.z; a1.w -= bp.w;
        __syncthreads();
        As[kq + 0][r0] = a0.x; As[kq + 1][r0] = a0.y; As[kq + 2][r0] = a0.z; As[kq + 3][r0] = a0.w;
        As[kq + 0][r1] = a1.x; As[kq + 1][r1] = a1.y; As[kq + 2][r1] = a1.z; As[kq + 3][r1] = a1.w;
        Bs[kq + 0][r0] = b0.x; Bs[kq + 1][r0] = b0.y; Bs[kq + 2][r0] = b0.z; Bs[kq + 3][r0] = b0.w;
        Bs[kq + 0][r1] = b1.x; Bs[kq + 1][r1] = b1.y; Bs[kq + 2][r1] = b1.z; Bs[kq + 3][r1] = b1.w;
        __syncthreads();
#pragma unroll
        for (int kk = 0; kk < 16; ++kk) {
            float4 av0 = *(const float4*)&As[kk][ty * 8];
            float4 av1 = *(const float4*)&As[kk][ty * 8 + 4];
            float4 bv0 = *(const float4*)&Bs[kk][tx * 8];
            float4 bv1 = *(const float4*)&Bs[kk][tx * 8 + 4];
            float a[8] = {av0.x, av0.y, av0.z, av0.w, av1.x, av1.y, av1.z, av1.w};
            float b[8] = {bv0.x, bv0.y, bv0.z, bv0.w, bv1.x, bv1.y, bv1.z, bv1.w};
#pragma unroll
            for (int i = 0; i < 8; ++i)
#pragma unroll
                for (int j = 0; j < 8; ++j)
                    acc[i][j] = fmaf(a[i], b[j], acc[i][j]);
        }
    }
#pragma unroll
    for (int i = 0; i < 8; ++i) {
        float* dst = z_pre + (size_t)(n0 + ty * 8 + i) * D_SAE + s0 + tx * 8;
        *(float4*)(dst)     = make_float4(acc[i][0], acc[i][1], acc[i][2], acc[i][3]);
        *(float4*)(dst + 4) = make_float4(acc[i][4], acc[i][5], acc[i][6], acc[i][7]);
    }
}

// fallback helper: build cmax from z_pre (only used with encode_gemm path)
__global__ __launch_bounds__(256) void cmax_from_zpre(
    const float* __restrict__ z_pre, unsigned int* __restrict__ cmax_g)
{
    const int row = blockIdx.x;
    const int c   = threadIdx.x;
    const float* src = z_pre + (size_t)row * D_SAE + c * 64;
    unsigned int mx = 0u;
    for (int e = 0; e < 64; ++e) mx = max(mx, f2su(src[e]));
    cmax_g[(size_t)row * NCHUNK + c] = mx;
}

// ---------------------------------------------------------------------------
// Kernel 2 (fused): top-K via chunk-max prefilter + sparse decode.
// sm32 = 32nd-largest chunk max => T >= sm32 and >=32 elems have su >= sm32.
// Candidates gathered from hot chunks only; exact rank by (su desc, idx asc)
// == lax.top_k. Then x_hat[row,:] = sum_j sval[j]*WdT[sidx[j],:] + b_dec +
// b_pre computed in the same block (list never leaves LDS).
// z must be pre-zeroed (encode epilogue zeroes it).
// ---------------------------------------------------------------------------
__global__ __launch_bounds__(256) void topk_decode5(
    const float* __restrict__ z_pre, const unsigned int* __restrict__ cmax_g,
    const unsigned short* __restrict__ WdT,
    const float* __restrict__ b_pre, const float* __restrict__ b_dec,
    float* __restrict__ z, float* __restrict__ x_hat)
{
    __shared__ unsigned int cm[NCHUNK];
    __shared__ unsigned int s_sm32;
    __shared__ int          hot[NCHUNK];
    __shared__ unsigned int nhot;
    __shared__ unsigned int cand_su[CAND_CAP];
    __shared__ int          cand_idx[CAND_CAP];
    __shared__ unsigned int cand_cnt;
    __shared__ int   sidx[KTOP];
    __shared__ float sval[KTOP];
    __shared__ unsigned int bsu[256];
    __shared__ int          bidx[256];

    const int row  = blockIdx.x;
    const int tid  = threadIdx.x;
    const int wid  = tid >> 6;
    const int lane = tid & 63;
    const float* src = z_pre + (size_t)row * D_SAE;

    if (tid == 0) { nhot = 0u; cand_cnt = 0u; }
    cm[tid] = cmax_g[(size_t)row * NCHUNK + tid];
    __syncthreads();

    // sm32 = chunk max at rank 31 under (value desc, index asc)
    {
        const unsigned int v = cm[tid];
        int r = 0;
        for (int j = 0; j < NCHUNK; ++j)
            r += (cm[j] > v) || (cm[j] == v && j < tid);
        if (r == KTOP - 1) s_sm32 = v;
    }
    __syncthreads();
    const unsigned int sm32 = s_sm32;

    if (cm[tid] >= sm32) { unsigned int p = atomicAdd(&nhot, 1u); hot[p] = tid; }
    __syncthreads();

    const int nh = (int)nhot;
    for (int h = wid; h < nh; h += 4) {
        const int i = hot[h] * 64 + lane;
        const unsigned int su = f2su(src[i]);
        if (su >= sm32) {
            unsigned int p = atomicAdd(&cand_cnt, 1u);
            if (p < (unsigned)CAND_CAP) { cand_su[p] = su; cand_idx[p] = i; }
        }
    }
    __syncthreads();

    if (cand_cnt <= (unsigned)CAND_CAP) {
        const int cnt = (int)cand_cnt;      // >= KTOP guaranteed
        for (int c = tid; c < cnt; c += 256) {
            const unsigned int s = cand_su[c];
            const int id = cand_idx[c];
            int r = 0;
            for (int j = 0; j < cnt; ++j) {
                const unsigned int sj = cand_su[j];
                r += (sj > s) || (sj == s && cand_idx[j] < id);
            }
            if (r < KTOP) { sidx[r] = id; sval[r] = su2f(s); }
        }
        __syncthreads();
    } else {
        // exact 32-round tournament over the full row (degenerate path)
        unsigned int last_su = 0xFFFFFFFFu; int last_idx = -1;
        for (int r = 0; r < KTOP; ++r) {
            unsigned int mysu = 0u; int myidx = 0x7FFFFFFF;
            for (int i = tid; i < D_SAE; i += 256) {
                const unsigned int su = f2su(src[i]);
                const bool after = (su < last_su) || (su == last_su && i > last_idx);
                if (after && (su > mysu || (su == mysu && i < myidx))) {
                    mysu = su; myidx = i;
                }
            }
            bsu[tid] = mysu; bidx[tid] = myidx;
            __syncthreads();
            if (tid == 0) {
                unsigned int bs = 0u; int bi = 0x7FFFFFFF;
                for (int j = 0; j < 256; ++j) {
                    if (bsu[j] > bs || (bsu[j] == bs && bidx[j] < bi)) {
                        bs = bsu[j]; bi = bidx[j];
                    }
                }
                sidx[r] = bi; sval[r] = su2f(bs);
                bsu[0] = bs; bidx[0] = bi;
            }
            __syncthreads();
            last_su = bsu[0]; last_idx = bidx[0];
            __syncthreads();
        }
    }

    // scatter winners into pre-zeroed z
    if (tid < KTOP) z[(size_t)row * D_SAE + sidx[tid]] = sval[tid];

    // decode: x_hat[row, d..d+3] = sum_j sval[j]*WdT[sidx[j], d..] + biases
    const int d = tid * 4;
    float4 bd = *(const float4*)(b_dec + d);
    float4 bp = *(const float4*)(b_pre + d);
    float4 acc = make_float4(bd.x + bp.x, bd.y + bp.y, bd.z + bp.z, bd.w + bp.w);
#pragma unroll
    for (int j = 0; j < KTOP; ++j) {
        const float v = sval[j];
        const ushort4 w = *(const ushort4*)(WdT + (size_t)sidx[j] * D_IN + d);
        acc.x = fmaf(v, __uint_as_float((unsigned int)w.x << 16), acc.x);
        acc.y = fmaf(v, __uint_as_float((unsigned int)w.y << 16), acc.y);
        acc.z = fmaf(v, __uint_as_float((unsigned int)w.z << 16), acc.z);
        acc.w = fmaf(v, __uint_as_float((unsigned int)w.w << 16), acc.w);
    }
    *(float4*)(x_hat + (size_t)row * D_IN + d) = acc;
}

// ---------------------------------------------------------------------------
// Kernel 2 (v4, no-workspace fallback path): full radix (unchanged).
// ---------------------------------------------------------------------------
__global__ __launch_bounds__(256) void topk_select4(
    const float* __restrict__ z_pre, float* __restrict__ z)
{
    __shared__ unsigned int hist[4096];
    __shared__ unsigned int cmax[256];
    __shared__ unsigned int sb[256];
    __shared__ unsigned int cand_su[CAND_CAP];
    __shared__ int          cand_idx[CAND_CAP];
    __shared__ unsigned int cand_cnt;
    __shared__ int          hot[256];
    __shared__ unsigned int nhot;
    __shared__ int   sel_list[KTOP];
    __shared__ float sel_val[KTOP];
    __shared__ int s_bin, s_gt;
    __shared__ unsigned int wcw[4];

    const int row  = blockIdx.x;
    const int tid  = threadIdx.x;
    const int wid  = tid >> 6;
    const int lane = tid & 63;
    const float* src = z_pre + (size_t)row * D_SAE;

    const int shifts[3] = {20, 8, 0};
    const int nbits_[3] = {12, 12, 8};

    cmax[tid] = 0u;
    if (tid == 0) { cand_cnt = 0u; nhot = 0u; }

    unsigned int prefix = 0u, pmask = 0u;
    int need = KTOP;
    int shiftF = 0;

    for (int level = 0; level < 3; ++level) {
        const int shift = shifts[level];
        const unsigned int nb = 1u << nbits_[level];
        for (int i = tid; i < (int)nb; i += 256) hist[i] = 0u;
        __syncthreads();
        for (int it = 0; it < 16; ++it) {
            const int i4 = (it * 256 + tid) * 4;
            float4 v = *(const float4*)(src + i4);
            unsigned int mx = 0u;
#pragma unroll
            for (int e = 0; e < 4; ++e) {
                unsigned int su = f2su((&v.x)[e]);
                if ((su & pmask) == prefix)
                    atomicAdd(&hist[(su >> shift) & (nb - 1u)], 1u);
                mx = su > mx ? su : mx;
            }
            if (level == 0) atomicMax(&cmax[i4 >> 6], mx);
        }
        __syncthreads();
        const int bpt = (int)(nb >> 8);
        unsigned int lsum = 0u;
        for (int j = 0; j < bpt; ++j) lsum += hist[tid * bpt + j];
        sb[tid] = lsum;
        __syncthreads();
        for (int off = 1; off < 256; off <<= 1) {
            unsigned int v = (tid + off < 256) ? sb[tid + off] : 0u;
            __syncthreads();
            sb[tid] += v;
            __syncthreads();
        }
        {
            unsigned int ge = sb[tid];
            unsigned int gt = (tid < 255) ? sb[tid + 1] : 0u;
            if ((int)ge >= need && (int)gt < need) {
                unsigned int run = gt;
                for (int j = bpt - 1; j >= 0; --j) {
                    unsigned int c = hist[tid * bpt + j];
                    if ((int)(run + c) >= need) { s_bin = tid * bpt + j; s_gt = (int)run; break; }
                    run += c;
                }
            }
        }
        __syncthreads();
        const int b = s_bin; const int gt = s_gt; const int cntb = (int)hist[b];
        __syncthreads();
        need -= gt;
        prefix |= ((unsigned int)b) << shift;
        pmask  |= (nb - 1u) << shift;
        if (cntb <= CAND_CAP) { shiftF = shift; break; }
        if (level == 2)       { shiftF = 0;     break; }
    }
    const unsigned int hb = prefix >> shiftF;

    if (cmax[tid] >= prefix) { unsigned int p = atomicAdd(&nhot, 1u); hot[p] = tid; }
    __syncthreads();

    __shared__ unsigned int outcnt;
    if (tid == 0) outcnt = 0u;
    __syncthreads();
    const int nh = (int)nhot;
    for (int h = wid; h < nh; h += 4) {
        const int i = hot[h] * 64 + lane;
        const float f = src[i];
        const unsigned int su = f2su(f);
        const unsigned int cls = su >> shiftF;
        if (cls > hb) {
            z[(size_t)row * D_SAE + i] = f;
        } else if (cls == hb) {
            unsigned int p = atomicAdd(&cand_cnt, 1u);
            if (p < (unsigned)CAND_CAP) { cand_su[p] = su; cand_idx[p] = i; }
        }
    }
    __syncthreads();

    if (cand_cnt <= (unsigned)CAND_CAP) {
        const int cnt = (int)cand_cnt;
        for (int c = tid; c < cnt; c += 256) {
            const unsigned int s = cand_su[c];
            const int id = cand_idx[c];
            int r = 0;
            for (int j = 0; j < cnt; ++j) {
                const unsigned int sj = cand_su[j];
                r += (sj > s) || (sj == s && cand_idx[j] < id);
            }
            if (r < need) { sel_list[r] = id; sel_val[r] = su2f(s); }
        }
        __syncthreads();
    } else {
        int cum = 0;
        for (int seg = 0; seg < 64; ++seg) {
            const int i = seg * 256 + tid;
            const bool m = (f2su(src[i]) == prefix);
            const unsigned long long bm = __ballot(m);
            if (lane == 0) wcw[wid] = (unsigned int)__popcll(bm);
            __syncthreads();
            int base = cum;
            for (int w = 0; w < wid; ++w) base += (int)wcw[w];
            const int r = base + (int)__popcll(bm & ((1ull << lane) - 1ull));
            if (m && r < need) { sel_list[r] = i; sel_val[r] = su2f(prefix); }
            cum += (int)(wcw[0] + wcw[1] + wcw[2] + wcw[3]);
            __syncthreads();
            if (cum >= need) break;
        }
        __syncthreads();
    }
    if (tid < need) z[(size_t)row * D_SAE + sel_list[tid]] = sel_val[tid];
}

// ---------------------------------------------------------------------------
// Kernel 3: W_dec transpose -> bf16 WdT (unchanged)
// ---------------------------------------------------------------------------
__global__ __launch_bounds__(256) void transpose_wdec_bf16(
    const float* __restrict__ in, unsigned short* __restrict__ out)
{
    __shared__ float tile[32][33];
    const int tid = threadIdx.x;
    const int lx = tid & 31, ly = tid >> 5;
    const int j0 = blockIdx.x * 32;
    const int d0 = blockIdx.y * 32;
#pragma unroll
    for (int r = 0; r < 4; ++r) {
        int d = d0 + ly + r * 8;
        tile[ly + r * 8][lx] = in[(size_t)d * D_SAE + j0 + lx];
    }
    __syncthreads();
#pragma unroll
    for (int r = 0; r < 4; ++r) {
        int j = j0 + ly + r * 8;
        out[(size_t)j * D_IN + d0 + lx] = f2bf(tile[lx][ly + r * 8]);
    }
}

// ---------------------------------------------------------------------------
// Kernel 4b: fallback decode (scans z, f32 W_dec; unchanged)
// ---------------------------------------------------------------------------
__global__ __launch_bounds__(256) void decode_slow(
    const float* __restrict__ W_dec, const float* __restrict__ z,
    const float* __restrict__ b_pre, const float* __restrict__ b_dec,
    float* __restrict__ x_hat)
{
    __shared__ int   sj[64];
    __shared__ float sv[64];
    __shared__ unsigned int cnt;
    __shared__ int s_m;
    const int row = blockIdx.x, tid = threadIdx.x;
    if (tid == 0) cnt = 0u;
    __syncthreads();
    const float* zr = z + (size_t)row * D_SAE;
    for (int i = tid; i < D_SAE; i += 256) {
        float v = zr[i];
        if (v != 0.0f) { unsigned p = atomicAdd(&cnt, 1u); if (p < 64u) { sj[p] = i; sv[p] = v; } }
    }
    __syncthreads();
    if (tid == 0) {
        int m = (int)(cnt < 64u ? cnt : 64u);
        for (int a = 1; a < m; ++a) {
            int vi = sj[a]; float vv = sv[a]; int b = a - 1;
            while (b >= 0 && sj[b] > vi) { sj[b + 1] = sj[b]; sv[b + 1] = sv[b]; --b; }
            sj[b + 1] = vi; sv[b + 1] = vv;
        }
        s_m = m;
    }
    __syncthreads();
    const int m = s_m;
    const int d = tid * 4;
    float4 bd = *(const float4*)(b_dec + d);
    float4 bp = *(const float4*)(b_pre + d);
    float4 acc = make_float4(bd.x + bp.x, bd.y + bp.y, bd.z + bp.z, bd.w + bp.w);
    for (int j = 0; j < m; ++j) {
        float v = sv[j];
        size_t c = (size_t)sj[j];
        acc.x = fmaf(v, W_dec[(size_t)(d + 0) * D_SAE + c], acc.x);
        acc.y = fmaf(v, W_dec[(size_t)(d + 1) * D_SAE + c], acc.y);
        acc.z = fmaf(v, W_dec[(size_t)(d + 2) * D_SAE + c], acc.z);
        acc.w = fmaf(v, W_dec[(size_t)(d + 3) * D_SAE + c], acc.w);
    }
    *(float4*)(x_hat + (size_t)row * D_IN + d) = acc;
}

// ---------------------------------------------------------------------------
extern "C" void kernel_launch(void* const* d_in, const int* in_sizes, int n_in,
                              void* d_out, int out_size, void* d_ws, size_t ws_size,
                              hipStream_t stream)
{
    const float* x     = (const float*)d_in[0];
    const float* b_pre = (const float*)d_in[1];
    const float* W_enc = (const float*)d_in[2];
    const float* W_dec = (const float*)d_in[3];
    const float* b_dec = (const float*)d_in[4];

    float* x_hat = (float*)d_out;
    float* z     = x_hat + (size_t)NROWS * D_IN;
    float* z_pre = z + (size_t)NROWS * D_SAE;

    const size_t wdt_bytes  = (size_t)D_SAE * D_IN * sizeof(unsigned short); // bf16
    const size_t list_bytes = (size_t)NROWS * KTOP * (sizeof(int) + sizeof(float));
    const size_t cmax_bytes = (size_t)NROWS * NCHUNK * sizeof(unsigned int);
    const size_t a2_bytes   = (size_t)NROWS * KSPLIT * sizeof(_Float16);
    const size_t b2_bytes   = (size_t)D_SAE * KSPLIT * sizeof(_Float16);

    char* p = (char*)d_ws;
    unsigned short* WdT  = (unsigned short*)p;  p += wdt_bytes;
    p += list_bytes;                            // (reserved; list now stays in LDS)
    unsigned int*   cmax = (unsigned int*)p;    p += cmax_bytes;
    _Float16*       A2   = (_Float16*)p;        p += a2_bytes;
    _Float16*       B2   = (_Float16*)p;

    const bool fast = (ws_size >= wdt_bytes + list_bytes + cmax_bytes);
    const bool mfma = (ws_size >= wdt_bytes + list_bytes + cmax_bytes + a2_bytes + b2_bytes);

    if (mfma && fast) {
        // z zeroed inside encode_mfma's epilogue (no memset needed)
        split_xw<<<NROWS + D_SAE, 256, 0, stream>>>(x, b_pre, W_enc, A2, B2);
        encode_mfma<<<dim3(D_SAE / 128, NROWS / 128), 256, 0, stream>>>(A2, B2, z_pre, cmax, z);
        transpose_wdec_bf16<<<dim3(D_SAE / 32, D_IN / 32), 256, 0, stream>>>(W_dec, WdT);
        topk_decode5<<<NROWS, 256, 0, stream>>>(z_pre, cmax, WdT, b_pre, b_dec, z, x_hat);
    } else {
        hipMemsetAsync(z, 0, (size_t)NROWS * D_SAE * sizeof(float), stream);
        encode_gemm<<<dim3(D_SAE / 128, NROWS / 128), 256, 0, stream>>>(x, b_pre, W_enc, z_pre);
        topk_select4<<<NROWS, 256, 0, stream>>>(z_pre, z);
        decode_slow<<<NROWS, 256, 0, stream>>>(W_dec, z, b_pre, b_dec, x_hat);
    }
}

// Round 13
// 1103.458 us; speedup vs baseline: 1.0773x; 1.0366x over previous
//
#include <hip/hip_runtime.h>

#define D_IN   1024
#define D_SAE  16384
#define KTOP   32
#define NROWS  8192
#define KSPLIT 3072   // A: [lo*2048 | hi | hi],  B: [hi | lo*2048 | hi]
#define LOSCALE 2048.0f
#define INV_LOSCALE 4.8828125e-4f   // 2^-11, exact
#define CAND_CAP 512
#define NCHUNK 256                   // 64-elem chunks per row

typedef _Float16 f16x8 __attribute__((ext_vector_type(8)));
typedef float    f32x4 __attribute__((ext_vector_type(4)));

__device__ __forceinline__ unsigned int f2su(float f) {
    unsigned int b = __float_as_uint(f);
    return (b & 0x80000000u) ? ~b : (b | 0x80000000u);
}
__device__ __forceinline__ float su2f(unsigned int su) {
    unsigned int fb = (su & 0x80000000u) ? (su & 0x7fffffffu) : ~su;
    return __uint_as_float(fb);
}
__device__ __forceinline__ unsigned short f2bf(float f) {   // RN bf16
    unsigned int u = __float_as_uint(f);
    return (unsigned short)((u + 0x7fffu + ((u >> 16) & 1u)) >> 16);
}

// ---------------------------------------------------------------------------
// Fused split kernel: fp32 -> (hi, lo*2048) fp16 for both x and W_enc.
// ---------------------------------------------------------------------------
__global__ __launch_bounds__(256) void split_xw(
    const float* __restrict__ x, const float* __restrict__ b_pre,
    const float* __restrict__ W_enc,
    _Float16* __restrict__ A2, _Float16* __restrict__ B2)
{
    const int b   = blockIdx.x;
    const int tid = threadIdx.x;
    const int k   = tid * 4;
    if (b < NROWS) {
        float4 v  = *(const float4*)(x + (size_t)b * D_IN + k);
        float4 bp = *(const float4*)(b_pre + k);
        v.x -= bp.x; v.y -= bp.y; v.z -= bp.z; v.w -= bp.w;
        _Float16 h[4], l[4];
        h[0] = (_Float16)v.x; l[0] = (_Float16)((v.x - (float)h[0]) * LOSCALE);
        h[1] = (_Float16)v.y; l[1] = (_Float16)((v.y - (float)h[1]) * LOSCALE);
        h[2] = (_Float16)v.z; l[2] = (_Float16)((v.z - (float)h[2]) * LOSCALE);
        h[3] = (_Float16)v.w; l[3] = (_Float16)((v.w - (float)h[3]) * LOSCALE);
        _Float16* row = A2 + (size_t)b * KSPLIT;
        *(ulong1*)(row + k)        = *(ulong1*)l;
        *(ulong1*)(row + 1024 + k) = *(ulong1*)h;
        *(ulong1*)(row + 2048 + k) = *(ulong1*)h;
    } else {
        const int s = b - NROWS;
        float4 v = *(const float4*)(W_enc + (size_t)s * D_IN + k);
        _Float16 h[4], l[4];
        h[0] = (_Float16)v.x; l[0] = (_Float16)((v.x - (float)h[0]) * LOSCALE);
        h[1] = (_Float16)v.y; l[1] = (_Float16)((v.y - (float)h[1]) * LOSCALE);
        h[2] = (_Float16)v.z; l[2] = (_Float16)((v.z - (float)h[2]) * LOSCALE);
        h[3] = (_Float16)v.w; l[3] = (_Float16)((v.w - (float)h[3]) * LOSCALE);
        _Float16* row = B2 + (size_t)s * KSPLIT;
        *(ulong1*)(row + k)        = *(ulong1*)h;
        *(ulong1*)(row + 1024 + k) = *(ulong1*)l;
        *(ulong1*)(row + 2048 + k) = *(ulong1*)h;
    }
}

// ---------------------------------------------------------------------------
// Kernel 1: encode MFMA GEMM -- R9-proven 128x128 / 2-barrier / T2 swizzle
// (deep-pipeline variants R5/R6/R11 all regressed; z-zero-in-epilogue R12
// regressed -> both reverted). Fused per-(row,chunk) max epilogue only.
// K=3072, acc rescale x2^-11 at k=2048.
// ---------------------------------------------------------------------------
__device__ __forceinline__ void gload_lds16(const void* g, void* lds) {
    __builtin_amdgcn_global_load_lds(
        (const __attribute__((address_space(1))) unsigned int*)g,
        (__attribute__((address_space(3))) unsigned int*)lds, 16, 0, 0);
}

__global__ __launch_bounds__(256, 2) void encode_mfma(
    const _Float16* __restrict__ A2, const _Float16* __restrict__ B2,
    float* __restrict__ z_pre, unsigned int* __restrict__ cmax_g)
{
    __shared__ _Float16 Asl[128 * 64];
    __shared__ _Float16 Bsl[128 * 64];

    const int tid  = threadIdx.x;
    const int wid  = tid >> 6;
    const int lane = tid & 63;
    const int wr   = wid >> 1;
    const int wc   = wid & 1;
    const int brow = blockIdx.y * 128;
    const int bcol = blockIdx.x * 128;

    const int srow = lane >> 3;
    const int scol = ((lane & 7) ^ srow) * 8;      // pre-swizzled global col

    const int fr = lane & 15;
    const int fq = lane >> 4;
    const int slot0 = ((0 + fq) ^ (fr & 7)) * 8;
    const int slot1 = ((4 + fq) ^ (fr & 7)) * 8;

    f32x4 acc[4][4] = {};

    for (int k0 = 0; k0 < KSPLIT; k0 += 64) {
        if (k0 == 2048) {
#pragma unroll
            for (int m = 0; m < 4; ++m)
#pragma unroll
                for (int n = 0; n < 4; ++n) {
                    acc[m][n][0] *= INV_LOSCALE;
                    acc[m][n][1] *= INV_LOSCALE;
                    acc[m][n][2] *= INV_LOSCALE;
                    acc[m][n][3] *= INV_LOSCALE;
                }
        }
#pragma unroll
        for (int t = 0; t < 4; ++t) {
            const int rg = (wid * 4 + t) * 8 + srow;
            const char* ldsA = (const char*)Asl + (wid * 4 + t) * 1024;
            const char* ldsB = (const char*)Bsl + (wid * 4 + t) * 1024;
            gload_lds16(A2 + (size_t)(brow + rg) * KSPLIT + k0 + scol, (void*)ldsA);
            gload_lds16(B2 + (size_t)(bcol + rg) * KSPLIT + k0 + scol, (void*)ldsB);
        }
        __syncthreads();

#pragma unroll
        for (int kk = 0; kk < 2; ++kk) {
            const int slot = kk ? slot1 : slot0;
            f16x8 a[4], b[4];
#pragma unroll
            for (int m = 0; m < 4; ++m)
                a[m] = *(const f16x8*)&Asl[(wr * 64 + m * 16 + fr) * 64 + slot];
#pragma unroll
            for (int n = 0; n < 4; ++n)
                b[n] = *(const f16x8*)&Bsl[(wc * 64 + n * 16 + fr) * 64 + slot];
#pragma unroll
            for (int m = 0; m < 4; ++m)
#pragma unroll
                for (int n = 0; n < 4; ++n)
                    acc[m][n] = __builtin_amdgcn_mfma_f32_16x16x32_f16(a[m], b[n], acc[m][n], 0, 0, 0);
        }
        __syncthreads();
    }

    // C write. C/D layout: col = lane&15, row = (lane>>4)*4 + j  [verified]
#pragma unroll
    for (int m = 0; m < 4; ++m) {
        const int r0 = brow + wr * 64 + m * 16 + fq * 4;
#pragma unroll
        for (int n = 0; n < 4; ++n) {
            float* dst = z_pre + (size_t)r0 * D_SAE + bcol + wc * 64 + n * 16 + fr;
#pragma unroll
            for (int j = 0; j < 4; ++j)
                dst[(size_t)j * D_SAE] = acc[m][n][j];
        }
    }

    // fused chunk-max: wave's 64-col chunk = [bcol + wc*64, +64), rows 64.
    const int chunk = (bcol >> 6) + wc;
#pragma unroll
    for (int m = 0; m < 4; ++m) {
        float v[4];
#pragma unroll
        for (int j = 0; j < 4; ++j)
            v[j] = fmaxf(fmaxf(acc[m][0][j], acc[m][1][j]),
                         fmaxf(acc[m][2][j], acc[m][3][j]));
#pragma unroll
        for (int mask = 1; mask < 16; mask <<= 1) {
#pragma unroll
            for (int j = 0; j < 4; ++j)
                v[j] = fmaxf(v[j], __shfl_xor(v[j], mask));
        }
        if (fr == 0) {
#pragma unroll
            for (int j = 0; j < 4; ++j) {
                const int row = brow + wr * 64 + m * 16 + fq * 4 + j;
                cmax_g[(size_t)row * NCHUNK + chunk] = f2su(v[j]);
            }
        }
    }
}

// ---------------------------------------------------------------------------
// Kernel 1 (fallback): fp32 vector GEMM (unchanged)
// ---------------------------------------------------------------------------
__global__ __launch_bounds__(256, 2) void encode_gemm(
    const float* __restrict__ x, const float* __restrict__ b_pre,
    const float* __restrict__ W_enc, float* __restrict__ z_pre)
{
    __shared__ float As[16][132];
    __shared__ float Bs[16][132];
    const int tid = threadIdx.x;
    const int n0  = blockIdx.y * 128;
    const int s0  = blockIdx.x * 128;
    const int ty  = tid >> 4;
    const int tx  = tid & 15;
    const int r0  = tid >> 2;
    const int r1  = r0 + 64;
    const int kq  = (tid & 3) * 4;
    float acc[8][8];
#pragma unroll
    for (int i = 0; i < 8; ++i)
#pragma unroll
        for (int j = 0; j < 8; ++j) acc[i][j] = 0.0f;
    const float* xA = x     + (size_t)n0 * D_IN;
    const float* wB = W_enc + (size_t)s0 * D_IN;
    for (int k0 = 0; k0 < D_IN; k0 += 16) {
        float4 a0 = *(const float4*)(xA + (size_t)r0 * D_IN + k0 + kq);
        float4 a1 = *(const float4*)(xA + (size_t)r1 * D_IN + k0 + kq);
        float4 b0 = *(const float4*)(wB + (size_t)r0 * D_IN + k0 + kq);
        float4 b1 = *(const float4*)(wB + (size_t)r1 * D_IN + k0 + kq);
        float4 bp = *(const float4*)(b_pre + k0 + kq);
        a0.x -= bp.x; a0.y -= bp.y; a0.z -= bp.z; a0.w -= bp.w;
        a1.x -= bp.x; a1.y -= bp.y; a1.z -= bp.z; a1.w -= bp.w;
        __syncthreads();
        As[kq + 0][r0] = a0.x; As[kq + 1][r0] = a0.y; As[kq + 2][r0] = a0.z; As[kq + 3][r0] = a0.w;
        As[kq + 0][r1] = a1.x; As[kq + 1][r1] = a1.y; As[kq + 2][r1] = a1.z; As[kq + 3][r1] = a1.w;
        Bs[kq + 0][r0] = b0.x; Bs[kq + 1][r0] = b0.y; Bs[kq + 2][r0] = b0.z; Bs[kq + 3][r0] = b0.w;
        Bs[kq + 0][r1] = b1.x; Bs[kq + 1][r1] = b1.y; Bs[kq + 2][r1] = b1.z; Bs[kq + 3][r1] = b1.w;
        __syncthreads();
#pragma unroll
        for (int kk = 0; kk < 16; ++kk) {
            float4 av0 = *(const float4*)&As[kk][ty * 8];
            float4 av1 = *(const float4*)&As[kk][ty * 8 + 4];
            float4 bv0 = *(const float4*)&Bs[kk][tx * 8];
            float4 bv1 = *(const float4*)&Bs[kk][tx * 8 + 4];
            float a[8] = {av0.x, av0.y, av0.z, av0.w, av1.x, av1.y, av1.z, av1.w};
            float b[8] = {bv0.x, bv0.y, bv0.z, bv0.w, bv1.x, bv1.y, bv1.z, bv1.w};
#pragma unroll
            for (int i = 0; i < 8; ++i)
#pragma unroll
                for (int j = 0; j < 8; ++j)
                    acc[i][j] = fmaf(a[i], b[j], acc[i][j]);
        }
    }
#pragma unroll
    for (int i = 0; i < 8; ++i) {
        float* dst = z_pre + (size_t)(n0 + ty * 8 + i) * D_SAE + s0 + tx * 8;
        *(float4*)(dst)     = make_float4(acc[i][0], acc[i][1], acc[i][2], acc[i][3]);
        *(float4*)(dst + 4) = make_float4(acc[i][4], acc[i][5], acc[i][6], acc[i][7]);
    }
}

// fallback helper: build cmax from z_pre (only used with encode_gemm path)
__global__ __launch_bounds__(256) void cmax_from_zpre(
    const float* __restrict__ z_pre, unsigned int* __restrict__ cmax_g)
{
    const int row = blockIdx.x;
    const int c   = threadIdx.x;
    const float* src = z_pre + (size_t)row * D_SAE + c * 64;
    unsigned int mx = 0u;
    for (int e = 0; e < 64; ++e) mx = max(mx, f2su(src[e]));
    cmax_g[(size_t)row * NCHUNK + c] = mx;
}

// ---------------------------------------------------------------------------
// Kernel 2 (fused): top-K via chunk-max prefilter + sparse decode (R12-
// proven). z must be pre-zeroed (hipMemsetAsync).
// ---------------------------------------------------------------------------
__global__ __launch_bounds__(256) void topk_decode5(
    const float* __restrict__ z_pre, const unsigned int* __restrict__ cmax_g,
    const unsigned short* __restrict__ WdT,
    const float* __restrict__ b_pre, const float* __restrict__ b_dec,
    float* __restrict__ z, float* __restrict__ x_hat)
{
    __shared__ unsigned int cm[NCHUNK];
    __shared__ unsigned int s_sm32;
    __shared__ int          hot[NCHUNK];
    __shared__ unsigned int nhot;
    __shared__ unsigned int cand_su[CAND_CAP];
    __shared__ int          cand_idx[CAND_CAP];
    __shared__ unsigned int cand_cnt;
    __shared__ int   sidx[KTOP];
    __shared__ float sval[KTOP];
    __shared__ unsigned int bsu[256];
    __shared__ int          bidx[256];

    const int row  = blockIdx.x;
    const int tid  = threadIdx.x;
    const int wid  = tid >> 6;
    const int lane = tid & 63;
    const float* src = z_pre + (size_t)row * D_SAE;

    if (tid == 0) { nhot = 0u; cand_cnt = 0u; }
    cm[tid] = cmax_g[(size_t)row * NCHUNK + tid];
    __syncthreads();

    // sm32 = chunk max at rank 31 under (value desc, index asc)
    {
        const unsigned int v = cm[tid];
        int r = 0;
        for (int j = 0; j < NCHUNK; ++j)
            r += (cm[j] > v) || (cm[j] == v && j < tid);
        if (r == KTOP - 1) s_sm32 = v;
    }
    __syncthreads();
    const unsigned int sm32 = s_sm32;

    if (cm[tid] >= sm32) { unsigned int p = atomicAdd(&nhot, 1u); hot[p] = tid; }
    __syncthreads();

    const int nh = (int)nhot;
    for (int h = wid; h < nh; h += 4) {
        const int i = hot[h] * 64 + lane;
        const unsigned int su = f2su(src[i]);
        if (su >= sm32) {
            unsigned int p = atomicAdd(&cand_cnt, 1u);
            if (p < (unsigned)CAND_CAP) { cand_su[p] = su; cand_idx[p] = i; }
        }
    }
    __syncthreads();

    if (cand_cnt <= (unsigned)CAND_CAP) {
        const int cnt = (int)cand_cnt;      // >= KTOP guaranteed
        for (int c = tid; c < cnt; c += 256) {
            const unsigned int s = cand_su[c];
            const int id = cand_idx[c];
            int r = 0;
            for (int j = 0; j < cnt; ++j) {
                const unsigned int sj = cand_su[j];
                r += (sj > s) || (sj == s && cand_idx[j] < id);
            }
            if (r < KTOP) { sidx[r] = id; sval[r] = su2f(s); }
        }
        __syncthreads();
    } else {
        // exact 32-round tournament over the full row (degenerate path)
        unsigned int last_su = 0xFFFFFFFFu; int last_idx = -1;
        for (int r = 0; r < KTOP; ++r) {
            unsigned int mysu = 0u; int myidx = 0x7FFFFFFF;
            for (int i = tid; i < D_SAE; i += 256) {
                const unsigned int su = f2su(src[i]);
                const bool after = (su < last_su) || (su == last_su && i > last_idx);
                if (after && (su > mysu || (su == mysu && i < myidx))) {
                    mysu = su; myidx = i;
                }
            }
            bsu[tid] = mysu; bidx[tid] = myidx;
            __syncthreads();
            if (tid == 0) {
                unsigned int bs = 0u; int bi = 0x7FFFFFFF;
                for (int j = 0; j < 256; ++j) {
                    if (bsu[j] > bs || (bsu[j] == bs && bidx[j] < bi)) {
                        bs = bsu[j]; bi = bidx[j];
                    }
                }
                sidx[r] = bi; sval[r] = su2f(bs);
                bsu[0] = bs; bidx[0] = bi;
            }
            __syncthreads();
            last_su = bsu[0]; last_idx = bidx[0];
            __syncthreads();
        }
    }

    // scatter winners into pre-zeroed z
    if (tid < KTOP) z[(size_t)row * D_SAE + sidx[tid]] = sval[tid];

    // decode: x_hat[row, d..d+3] = sum_j sval[j]*WdT[sidx[j], d..] + biases
    const int d = tid * 4;
    float4 bd = *(const float4*)(b_dec + d);
    float4 bp = *(const float4*)(b_pre + d);
    float4 acc = make_float4(bd.x + bp.x, bd.y + bp.y, bd.z + bp.z, bd.w + bp.w);
#pragma unroll
    for (int j = 0; j < KTOP; ++j) {
        const float v = sval[j];
        const ushort4 w = *(const ushort4*)(WdT + (size_t)sidx[j] * D_IN + d);
        acc.x = fmaf(v, __uint_as_float((unsigned int)w.x << 16), acc.x);
        acc.y = fmaf(v, __uint_as_float((unsigned int)w.y << 16), acc.y);
        acc.z = fmaf(v, __uint_as_float((unsigned int)w.z << 16), acc.z);
        acc.w = fmaf(v, __uint_as_float((unsigned int)w.w << 16), acc.w);
    }
    *(float4*)(x_hat + (size_t)row * D_IN + d) = acc;
}

// ---------------------------------------------------------------------------
// Kernel 2 (v4, no-workspace fallback path): full radix (unchanged).
// ---------------------------------------------------------------------------
__global__ __launch_bounds__(256) void topk_select4(
    const float* __restrict__ z_pre, float* __restrict__ z)
{
    __shared__ unsigned int hist[4096];
    __shared__ unsigned int cmax[256];
    __shared__ unsigned int sb[256];
    __shared__ unsigned int cand_su[CAND_CAP];
    __shared__ int          cand_idx[CAND_CAP];
    __shared__ unsigned int cand_cnt;
    __shared__ int          hot[256];
    __shared__ unsigned int nhot;
    __shared__ int   sel_list[KTOP];
    __shared__ float sel_val[KTOP];
    __shared__ int s_bin, s_gt;
    __shared__ unsigned int wcw[4];

    const int row  = blockIdx.x;
    const int tid  = threadIdx.x;
    const int wid  = tid >> 6;
    const int lane = tid & 63;
    const float* src = z_pre + (size_t)row * D_SAE;

    const int shifts[3] = {20, 8, 0};
    const int nbits_[3] = {12, 12, 8};

    cmax[tid] = 0u;
    if (tid == 0) { cand_cnt = 0u; nhot = 0u; }

    unsigned int prefix = 0u, pmask = 0u;
    int need = KTOP;
    int shiftF = 0;

    for (int level = 0; level < 3; ++level) {
        const int shift = shifts[level];
        const unsigned int nb = 1u << nbits_[level];
        for (int i = tid; i < (int)nb; i += 256) hist[i] = 0u;
        __syncthreads();
        for (int it = 0; it < 16; ++it) {
            const int i4 = (it * 256 + tid) * 4;
            float4 v = *(const float4*)(src + i4);
            unsigned int mx = 0u;
#pragma unroll
            for (int e = 0; e < 4; ++e) {
                unsigned int su = f2su((&v.x)[e]);
                if ((su & pmask) == prefix)
                    atomicAdd(&hist[(su >> shift) & (nb - 1u)], 1u);
                mx = su > mx ? su : mx;
            }
            if (level == 0) atomicMax(&cmax[i4 >> 6], mx);
        }
        __syncthreads();
        const int bpt = (int)(nb >> 8);
        unsigned int lsum = 0u;
        for (int j = 0; j < bpt; ++j) lsum += hist[tid * bpt + j];
        sb[tid] = lsum;
        __syncthreads();
        for (int off = 1; off < 256; off <<= 1) {
            unsigned int v = (tid + off < 256) ? sb[tid + off] : 0u;
            __syncthreads();
            sb[tid] += v;
            __syncthreads();
        }
        {
            unsigned int ge = sb[tid];
            unsigned int gt = (tid < 255) ? sb[tid + 1] : 0u;
            if ((int)ge >= need && (int)gt < need) {
                unsigned int run = gt;
                for (int j = bpt - 1; j >= 0; --j) {
                    unsigned int c = hist[tid * bpt + j];
                    if ((int)(run + c) >= need) { s_bin = tid * bpt + j; s_gt = (int)run; break; }
                    run += c;
                }
            }
        }
        __syncthreads();
        const int b = s_bin; const int gt = s_gt; const int cntb = (int)hist[b];
        __syncthreads();
        need -= gt;
        prefix |= ((unsigned int)b) << shift;
        pmask  |= (nb - 1u) << shift;
        if (cntb <= CAND_CAP) { shiftF = shift; break; }
        if (level == 2)       { shiftF = 0;     break; }
    }
    const unsigned int hb = prefix >> shiftF;

    if (cmax[tid] >= prefix) { unsigned int p = atomicAdd(&nhot, 1u); hot[p] = tid; }
    __syncthreads();

    __shared__ unsigned int outcnt;
    if (tid == 0) outcnt = 0u;
    __syncthreads();
    const int nh = (int)nhot;
    for (int h = wid; h < nh; h += 4) {
        const int i = hot[h] * 64 + lane;
        const float f = src[i];
        const unsigned int su = f2su(f);
        const unsigned int cls = su >> shiftF;
        if (cls > hb) {
            z[(size_t)row * D_SAE + i] = f;
        } else if (cls == hb) {
            unsigned int p = atomicAdd(&cand_cnt, 1u);
            if (p < (unsigned)CAND_CAP) { cand_su[p] = su; cand_idx[p] = i; }
        }
    }
    __syncthreads();

    if (cand_cnt <= (unsigned)CAND_CAP) {
        const int cnt = (int)cand_cnt;
        for (int c = tid; c < cnt; c += 256) {
            const unsigned int s = cand_su[c];
            const int id = cand_idx[c];
            int r = 0;
            for (int j = 0; j < cnt; ++j) {
                const unsigned int sj = cand_su[j];
                r += (sj > s) || (sj == s && cand_idx[j] < id);
            }
            if (r < need) { sel_list[r] = id; sel_val[r] = su2f(s); }
        }
        __syncthreads();
    } else {
        int cum = 0;
        for (int seg = 0; seg < 64; ++seg) {
            const int i = seg * 256 + tid;
            const bool m = (f2su(src[i]) == prefix);
            const unsigned long long bm = __ballot(m);
            if (lane == 0) wcw[wid] = (unsigned int)__popcll(bm);
            __syncthreads();
            int base = cum;
            for (int w = 0; w < wid; ++w) base += (int)wcw[w];
            const int r = base + (int)__popcll(bm & ((1ull << lane) - 1ull));
            if (m && r < need) { sel_list[r] = i; sel_val[r] = su2f(prefix); }
            cum += (int)(wcw[0] + wcw[1] + wcw[2] + wcw[3]);
            __syncthreads();
            if (cum >= need) break;
        }
        __syncthreads();
    }
    if (tid < need) z[(size_t)row * D_SAE + sel_list[tid]] = sel_val[tid];
}

// ---------------------------------------------------------------------------
// Kernel 3: W_dec transpose -> bf16 WdT (unchanged)
// ---------------------------------------------------------------------------
__global__ __launch_bounds__(256) void transpose_wdec_bf16(
    const float* __restrict__ in, unsigned short* __restrict__ out)
{
    __shared__ float tile[32][33];
    const int tid = threadIdx.x;
    const int lx = tid & 31, ly = tid >> 5;
    const int j0 = blockIdx.x * 32;
    const int d0 = blockIdx.y * 32;
#pragma unroll
    for (int r = 0; r < 4; ++r) {
        int d = d0 + ly + r * 8;
        tile[ly + r * 8][lx] = in[(size_t)d * D_SAE + j0 + lx];
    }
    __syncthreads();
#pragma unroll
    for (int r = 0; r < 4; ++r) {
        int j = j0 + ly + r * 8;
        out[(size_t)j * D_IN + d0 + lx] = f2bf(tile[lx][ly + r * 8]);
    }
}

// ---------------------------------------------------------------------------
// Kernel 4b: fallback decode (scans z, f32 W_dec; unchanged)
// ---------------------------------------------------------------------------
__global__ __launch_bounds__(256) void decode_slow(
    const float* __restrict__ W_dec, const float* __restrict__ z,
    const float* __restrict__ b_pre, const float* __restrict__ b_dec,
    float* __restrict__ x_hat)
{
    __shared__ int   sj[64];
    __shared__ float sv[64];
    __shared__ unsigned int cnt;
    __shared__ int s_m;
    const int row = blockIdx.x, tid = threadIdx.x;
    if (tid == 0) cnt = 0u;
    __syncthreads();
    const float* zr = z + (size_t)row * D_SAE;
    for (int i = tid; i < D_SAE; i += 256) {
        float v = zr[i];
        if (v != 0.0f) { unsigned p = atomicAdd(&cnt, 1u); if (p < 64u) { sj[p] = i; sv[p] = v; } }
    }
    __syncthreads();
    if (tid == 0) {
        int m = (int)(cnt < 64u ? cnt : 64u);
        for (int a = 1; a < m; ++a) {
            int vi = sj[a]; float vv = sv[a]; int b = a - 1;
            while (b >= 0 && sj[b] > vi) { sj[b + 1] = sj[b]; sv[b + 1] = sv[b]; --b; }
            sj[b + 1] = vi; sv[b + 1] = vv;
        }
        s_m = m;
    }
    __syncthreads();
    const int m = s_m;
    const int d = tid * 4;
    float4 bd = *(const float4*)(b_dec + d);
    float4 bp = *(const float4*)(b_pre + d);
    float4 acc = make_float4(bd.x + bp.x, bd.y + bp.y, bd.z + bp.z, bd.w + bp.w);
    for (int j = 0; j < m; ++j) {
        float v = sv[j];
        size_t c = (size_t)sj[j];
        acc.x = fmaf(v, W_dec[(size_t)(d + 0) * D_SAE + c], acc.x);
        acc.y = fmaf(v, W_dec[(size_t)(d + 1) * D_SAE + c], acc.y);
        acc.z = fmaf(v, W_dec[(size_t)(d + 2) * D_SAE + c], acc.z);
        acc.w = fmaf(v, W_dec[(size_t)(d + 3) * D_SAE + c], acc.w);
    }
    *(float4*)(x_hat + (size_t)row * D_IN + d) = acc;
}

// ---------------------------------------------------------------------------
extern "C" void kernel_launch(void* const* d_in, const int* in_sizes, int n_in,
                              void* d_out, int out_size, void* d_ws, size_t ws_size,
                              hipStream_t stream)
{
    const float* x     = (const float*)d_in[0];
    const float* b_pre = (const float*)d_in[1];
    const float* W_enc = (const float*)d_in[2];
    const float* W_dec = (const float*)d_in[3];
    const float* b_dec = (const float*)d_in[4];

    float* x_hat = (float*)d_out;
    float* z     = x_hat + (size_t)NROWS * D_IN;
    float* z_pre = z + (size_t)NROWS * D_SAE;

    const size_t wdt_bytes  = (size_t)D_SAE * D_IN * sizeof(unsigned short); // bf16
    const size_t list_bytes = (size_t)NROWS * KTOP * (sizeof(int) + sizeof(float));
    const size_t cmax_bytes = (size_t)NROWS * NCHUNK * sizeof(unsigned int);
    const size_t a2_bytes   = (size_t)NROWS * KSPLIT * sizeof(_Float16);
    const size_t b2_bytes   = (size_t)D_SAE * KSPLIT * sizeof(_Float16);

    char* p = (char*)d_ws;
    unsigned short* WdT  = (unsigned short*)p;  p += wdt_bytes;
    p += list_bytes;                            // (reserved)
    unsigned int*   cmax = (unsigned int*)p;    p += cmax_bytes;
    _Float16*       A2   = (_Float16*)p;        p += a2_bytes;
    _Float16*       B2   = (_Float16*)p;

    const bool fast = (ws_size >= wdt_bytes + list_bytes + cmax_bytes);
    const bool mfma = (ws_size >= wdt_bytes + list_bytes + cmax_bytes + a2_bytes + b2_bytes);

    // z written sparsely by top-k -- zero it up front (pure-BW memset; R12
    // showed folding this into the encode epilogue costs more than it saves)
    hipMemsetAsync(z, 0, (size_t)NROWS * D_SAE * sizeof(float), stream);

    if (mfma && fast) {
        split_xw<<<NROWS + D_SAE, 256, 0, stream>>>(x, b_pre, W_enc, A2, B2);
        encode_mfma<<<dim3(D_SAE / 128, NROWS / 128), 256, 0, stream>>>(A2, B2, z_pre, cmax);
        transpose_wdec_bf16<<<dim3(D_SAE / 32, D_IN / 32), 256, 0, stream>>>(W_dec, WdT);
        topk_decode5<<<NROWS, 256, 0, stream>>>(z_pre, cmax, WdT, b_pre, b_dec, z, x_hat);
    } else {
        encode_gemm<<<dim3(D_SAE / 128, NROWS / 128), 256, 0, stream>>>(x, b_pre, W_enc, z_pre);
        topk_select4<<<NROWS, 256, 0, stream>>>(z_pre, z);
        decode_slow<<<NROWS, 256, 0, stream>>>(W_dec, z, b_pre, b_dec, x_hat);
    }
}